// Round 6
// baseline (342.113 us; speedup 1.0000x reference)
//
#include <hip/hip_runtime.h>
#include <hip/hip_bf16.h>
#include <math.h>

typedef float f32x4 __attribute__((ext_vector_type(4)));
typedef __bf16 bf16x8 __attribute__((ext_vector_type(8)));

#define PI2 6.283185307179586

static __device__ __forceinline__ unsigned short f2b(float f) {
  __hip_bfloat16 h = __float2bfloat16(f);
  return reinterpret_cast<unsigned short&>(h);
}

// ---------------- setup: pos table (ushort [64][36]) + twiddle tables ----------------
__global__ __launch_bounds__(256) void setup_tables_kernel(
    unsigned short* __restrict__ post16, __hip_bfloat16* __restrict__ Tt,
    __hip_bfloat16* __restrict__ Ub) {
  const int tid = threadIdx.x;
  __shared__ int cnt[64];
  __shared__ int pref[64];

  if (tid < 64) {
    int i = tid;
    double ys = -1.0 + (double)i * (2.0 / 63.0);
    int cRow = 0;
    for (int j = 0; j < 33; ++j) {
      double xs = (double)j / 32.0;
      bool m = (fabs(xs) < 0.1) || (fabs(ys) < 0.1) || (xs * xs + ys * ys <= 0.16);
      cRow += m ? 1 : 0;
    }
    cnt[i] = cRow;
  }
  __syncthreads();
  if (tid == 0) {
    int s = 0;
    for (int i = 0; i < 64; ++i) { pref[i] = s; s += cnt[i]; }
  }
  __syncthreads();
  if (tid < 64) {
    int i = tid;
    int k = pref[i];
    double ys = -1.0 + (double)i * (2.0 / 63.0);
    for (int j = 0; j < 36; ++j) {
      unsigned short v = 0xFFFFu;
      if (j < 33) {
        double xs = (double)j / 32.0;
        bool m = (fabs(xs) < 0.1) || (fabs(ys) < 0.1) || (xs * xs + ys * ys <= 0.16);
        if (m) v = (unsigned short)(k++);
      }
      post16[i * 36 + j] = v;
    }
  }

  // Tt[80][64]: rows 0..32 = cos(2*pi*n*w/64), rows 40..72 = -sin, else 0
  for (int idx = tid; idx < 80 * 64; idx += 256) {
    int n = idx >> 6, w = idx & 63;
    float v = 0.0f;
    if (n < 33) {
      int r = (n * w) & 63;
      v = cosf((float)(PI2 / 64.0) * (float)r);
    } else if (n >= 40 && n < 73) {
      int r = ((n - 40) * w) & 63;
      v = -sinf((float)(PI2 / 64.0) * (float)r);
    }
    Tt[idx] = __float2bfloat16(v);
  }

  // Ub[128][128]: row u'=u   : [cos | sin], row u'=64+u : [-sin | cos], v=(u+32)&63
  for (int idx = tid; idx < 128 * 128; idx += 256) {
    int up = idx >> 7, kk = idx & 127;
    int u = up & 63;
    int vfreq = (u + 32) & 63;
    int h = kk & 63;
    int r = (vfreq * h) & 63;
    float cv, sv;
    __sincosf((float)(PI2 / 64.0) * (float)r, &sv, &cv);
    float val;
    if (up < 64) val = (kk < 64) ? cv : sv;
    else         val = (kk < 64) ? -sv : cv;
    Ub[idx] = __float2bfloat16(val);
  }
}

// ---------------- weight fp32 -> bf16, K-padded (B^T layout) ----------------
__global__ __launch_bounds__(256) void wconv_kernel(
    const float* __restrict__ W, __hip_bfloat16* __restrict__ wB,
    int N, int Kd, int Kp) {
  int total = N * Kp;
  for (int idx = blockIdx.x * 256 + threadIdx.x; idx < total; idx += gridDim.x * 256) {
    int e = idx / Kp;
    int f = idx - e * Kp;
    float v = (f < Kd) ? W[(size_t)e * Kd + f] : 0.0f;
    wB[idx] = __float2bfloat16(v);
  }
}

// -------- fused MFMA rfft2 + fftshift + gather: 2 waves/image, 8 images/block --------
// Persistent wave-pair loops over 8 consecutive images; next image's x is
// prefetched into registers after phase C and written to LDS in the tail
// (after bar3) -- HBM latency hides under stage-2 MFMA + gather + copy.
// LDS/block: Xbf/Sout union 8704 + featbuf 2176 + post 4608 = 15488 B.
#define IMGS 8
#define IMGB 10880
#define POSTB 4608

__global__ __launch_bounds__(128, 4) void fft_mfma_kernel(
    const float* __restrict__ x,
    const __hip_bfloat16* __restrict__ Tt,     // [80][64]
    const __hip_bfloat16* __restrict__ Ub,     // [128][128]
    const unsigned short* __restrict__ post16, // [64][36]
    __hip_bfloat16* __restrict__ feats,
    int K, int Kp) {
  __shared__ __align__(16) char lds[IMGB + POSTB];
  const int tid = threadIdx.x;
  const int lane = tid & 63;
  const int wp = tid >> 6;     // wave 0/1: X-row half & u' half
  const int l4 = lane & 15;
  const int q = lane >> 4;
  char* ibuf = lds;                                   // Xbf/Sout union [0,8704)
  unsigned int* fb = (unsigned int*)(lds + 8704);     // featbuf 2176 B
  unsigned short* fbs = (unsigned short*)fb;
  unsigned short* postl = (unsigned short*)(lds + IMGB);

  const int img0 = blockIdx.x * IMGS;

  // ---- prologue: post table -> LDS (1152 dwords over 128 threads) ----
  {
    const unsigned int* src = reinterpret_cast<const unsigned int*>(post16);
    unsigned int* dst = reinterpret_cast<unsigned int*>(postl);
    #pragma unroll
    for (int i = 0; i < 9; ++i) dst[i * 128 + tid] = src[i * 128 + tid];
  }

  // ---- prologue: load image 0 (own half) -> regs -> swizzled Xbf ----
  float4 st[8];
  {
    const float* xi = x + (size_t)img0 * 4096;
    #pragma unroll
    for (int r = 0; r < 8; ++r) {
      int row = wp * 32 + r * 4 + q;
      st[r] = *reinterpret_cast<const float4*>(xi + row * 64 + l4 * 4);
    }
    #pragma unroll
    for (int r = 0; r < 8; ++r) {
      int row = wp * 32 + r * 4 + q;
      int off = row * 128 + (((l4 >> 1) ^ (row & 7)) * 16 + (l4 & 1) * 8);
      ushort4 b;
      b.x = f2b(st[r].x); b.y = f2b(st[r].y); b.z = f2b(st[r].z); b.w = f2b(st[r].w);
      *reinterpret_cast<ushort4*>(ibuf + off) = b;
    }
  }

  for (int it = 0; it < IMGS; ++it) {
    const int img = img0 + it;
    const int sp = img / 3;
    const int c = img - sp * 3;

    // ---- phase B: stage 1 MFMA  S[own 32 rows][80] = X * Tt^T  (20 MFMA)
    f32x4 acc1[2][5] = {};
    #pragma unroll
    for (int ks = 0; ks < 2; ++ks) {
      bf16x8 a1[2], b1[5];
      #pragma unroll
      for (int am = 0; am < 2; ++am) {
        int h = wp * 32 + am * 16 + l4;
        int kg = ks * 4 + q;
        a1[am] = *reinterpret_cast<const bf16x8*>(ibuf + h * 128 + ((kg ^ (h & 7)) * 16));
      }
      #pragma unroll
      for (int n = 0; n < 5; ++n) {
        int row = n * 16 + l4;
        b1[n] = *reinterpret_cast<const bf16x8*>(
            (const char*)Tt + row * 128 + ks * 64 + q * 16);
      }
      #pragma unroll
      for (int am = 0; am < 2; ++am)
        #pragma unroll
        for (int n = 0; n < 5; ++n)
          acc1[am][n] = __builtin_amdgcn_mfma_f32_16x16x32_bf16(a1[am], b1[n], acc1[am][n], 0, 0, 0);
    }

    __syncthreads();   // bar1: both waves' B-reads done (C overlays Xbf)

    // ---- phase C: write Sout[j<33][kk] (Re kk=h, Im kk=64+h), packed ushort4
    #pragma unroll
    for (int n = 0; n < 5; ++n) {
      int col = n * 16 + l4;
      bool isRe = (col < 33);
      bool isIm = (col >= 40 && col < 73);
      if (!(isRe || isIm)) continue;
      int j = isRe ? col : (col - 40);
      #pragma unroll
      for (int am = 0; am < 2; ++am) {
        int h0 = wp * 32 + am * 16 + q * 4;           // kk&7 stays in one 8-group
        int kk0 = isRe ? h0 : (h0 + 64);
        int off = j * 256 + (((kk0 >> 3) ^ (j & 15)) * 16 + (kk0 & 7) * 2);
        ushort4 b;
        b.x = f2b(acc1[am][n][0]); b.y = f2b(acc1[am][n][1]);
        b.z = f2b(acc1[am][n][2]); b.w = f2b(acc1[am][n][3]);
        *reinterpret_cast<ushort4*>(ibuf + off) = b;
      }
    }

    // ---- prefetch next image (own half) into regs; consumed in tail ----
    if (it + 1 < IMGS) {
      const float* xn = x + (size_t)(img + 1) * 4096;
      #pragma unroll
      for (int r = 0; r < 8; ++r) {
        int row = wp * 32 + r * 4 + q;
        st[r] = *reinterpret_cast<const float4*>(xn + row * 64 + l4 * 4);
      }
    }

    __syncthreads();   // bar2: Sout complete (both kk halves)

    // ---- phase D: stage 2 MFMA  C2[48 j-rows][own u' half] = Sout * Ub^T  (48 MFMA)
    f32x4 acc2[3][4] = {};
    #pragma unroll
    for (int ks = 0; ks < 4; ++ks) {
      bf16x8 a2[3], b2[4];
      #pragma unroll
      for (int m = 0; m < 3; ++m) {
        int j = m * 16 + l4;
        if (j > 33) j = 33;                           // clamp into 34-row buffer
        int kg = ks * 4 + q;
        a2[m] = *reinterpret_cast<const bf16x8*>(ibuf + j * 256 + ((kg ^ (j & 15)) * 16));
      }
      #pragma unroll
      for (int n = 0; n < 4; ++n) {
        int rowg = (wp * 4 + n) * 16 + l4;
        b2[n] = *reinterpret_cast<const bf16x8*>(
            (const char*)Ub + rowg * 256 + ks * 64 + q * 16);
      }
      #pragma unroll
      for (int m = 0; m < 3; ++m)
        #pragma unroll
        for (int n = 0; n < 4; ++n)
          acc2[m][n] = __builtin_amdgcn_mfma_f32_16x16x32_bf16(a2[m], b2[n], acc2[m][n], 0, 0, 0);
    }

    // ---- phase E: masked gather -> featbuf (wave 0: Re, wave 1: Im)
    {
      const int base = wp ? K : 0;
      #pragma unroll
      for (int n = 0; n < 4; ++n) {
        int u = n * 16 + l4;
        #pragma unroll
        for (int m = 0; m < 3; ++m) {
          int j0 = m * 16 + q * 4;
          if (j0 > 32) continue;
          ushort4 kv = *reinterpret_cast<const ushort4*>(postl + u * 36 + j0);
          #pragma unroll
          for (int r = 0; r < 4; ++r) {
            int j = j0 + r;
            unsigned short k = (&kv.x)[r];
            if (j < 33 && k != 0xFFFFu)
              fbs[base + k] = f2b(acc2[m][n][r]);
          }
        }
      }
    }

    __syncthreads();   // bar3: featbuf complete; Sout reads done (tail overlays)

    // ---- copy featbuf -> feats (two contiguous dword runs) + zero K-pad
    {
      size_t obase = (size_t)sp * Kp;
      unsigned int* gRe = reinterpret_cast<unsigned int*>(feats + obase + (size_t)c * K);
      unsigned int* gIm = reinterpret_cast<unsigned int*>(feats + obase + (size_t)3 * K + (size_t)c * K);
      const int KD2 = K / 2;   // 271 dwords per run
      for (int i = tid; i < KD2; i += 128) {
        gRe[i] = fb[i];
        gIm[i] = fb[KD2 + i];
      }
      if (wp == 0 && c == 2) {
        unsigned int* gp = reinterpret_cast<unsigned int*>(feats + obase + (size_t)6 * K);
        int padDw = (Kp - 6 * K) / 2;
        if (lane < padDw) gp[lane] = 0u;
      }
    }

    // ---- tail: write prefetched next-X (own half) over Sout region ----
    if (it + 1 < IMGS) {
      #pragma unroll
      for (int r = 0; r < 8; ++r) {
        int row = wp * 32 + r * 4 + q;
        int off = row * 128 + (((l4 >> 1) ^ (row & 7)) * 16 + (l4 & 1) * 8);
        ushort4 b;
        b.x = f2b(st[r].x); b.y = f2b(st[r].y); b.z = f2b(st[r].z); b.w = f2b(st[r].w);
        *reinterpret_cast<ushort4*>(ibuf + off) = b;
      }
    }
    // no barrier needed: next phase B reads only this wave's own Xbf half
  }
}

// ---------------- bf16 MFMA GEMM: out[M][N] = A[M][Kp] * B[N][Kp]^T + bias ----------------
#define BM 128
#define BN 128
#define BKK 64

__global__ __launch_bounds__(256) void gemm_bias_kernel(
    const __hip_bfloat16* __restrict__ A, const __hip_bfloat16* __restrict__ B,
    const float* __restrict__ bias, float* __restrict__ C,
    int M, int N, int Kp) {
  __shared__ __align__(16) unsigned short As[BM * BKK];
  __shared__ __align__(16) unsigned short Bs[BN * BKK];

  const int tid = threadIdx.x;
  const int lane = tid & 63;
  const int wid = tid >> 6;
  const int wm = wid & 1;
  const int wn = wid >> 1;
  const int nbm = M / BM;
  const int bm = blockIdx.x % nbm;
  const int bn = blockIdx.x / nbm;
  const int row0A = bm * BM;
  const int row0B = bn * BN;

  f32x4 acc[4][4] = {};

  for (int k0 = 0; k0 < Kp; k0 += BKK) {
    #pragma unroll
    for (int i = 0; i < 4; ++i) {
      int qc = i * 256 + tid;
      int r = qc >> 3;
      int cb = (qc & 7) * 16;
      const char* gA = (const char*)A + ((size_t)(row0A + r) * Kp + k0) * 2 + cb;
      const char* gB = (const char*)B + ((size_t)(row0B + r) * Kp + k0) * 2 + cb;
      char* lA = (char*)As + (size_t)(i * 256 + wid * 64) * 16;
      char* lB = (char*)Bs + (size_t)(i * 256 + wid * 64) * 16;
      __builtin_amdgcn_global_load_lds((const __attribute__((address_space(1))) void*)gA,
                                       (__attribute__((address_space(3))) void*)lA, 16, 0, 0);
      __builtin_amdgcn_global_load_lds((const __attribute__((address_space(1))) void*)gB,
                                       (__attribute__((address_space(3))) void*)lB, 16, 0, 0);
    }
    __syncthreads();

    #pragma unroll
    for (int kk = 0; kk < 2; ++kk) {
      bf16x8 afr[4], bfr[4];
      const int ke = kk * 32 + (lane >> 4) * 8;
      #pragma unroll
      for (int m = 0; m < 4; ++m) {
        int rowA = wm * 64 + m * 16 + (lane & 15);
        afr[m] = *reinterpret_cast<const bf16x8*>(&As[rowA * BKK + ke]);
      }
      #pragma unroll
      for (int n = 0; n < 4; ++n) {
        int rowB = wn * 64 + n * 16 + (lane & 15);
        bfr[n] = *reinterpret_cast<const bf16x8*>(&Bs[rowB * BKK + ke]);
      }
      #pragma unroll
      for (int m = 0; m < 4; ++m)
        #pragma unroll
        for (int n = 0; n < 4; ++n)
          acc[m][n] = __builtin_amdgcn_mfma_f32_16x16x32_bf16(afr[m], bfr[n], acc[m][n], 0, 0, 0);
    }
    __syncthreads();
  }

  #pragma unroll
  for (int n = 0; n < 4; ++n) {
    int gcol = row0B + wn * 64 + n * 16 + (lane & 15);
    float bv = bias[gcol];
    #pragma unroll
    for (int m = 0; m < 4; ++m) {
      int grow0 = row0A + wm * 64 + m * 16 + (lane >> 4) * 4;
      #pragma unroll
      for (int r = 0; r < 4; ++r) {
        C[(size_t)(grow0 + r) * N + gcol] = acc[m][n][r] + bv;
      }
    }
  }
}

extern "C" void kernel_launch(void* const* d_in, const int* in_sizes, int n_in,
                              void* d_out, int out_size, void* d_ws, size_t ws_size,
                              hipStream_t stream) {
  const float* x = (const float*)d_in[0];
  const float* W = (const float*)d_in[2];
  const float* bias = (const float*)d_in[3];
  float* out = (float*)d_out;

  const int ENC = in_sizes[3];                 // 1024
  const int Kd = in_sizes[2] / ENC;            // 6*K = 3252
  const int K = Kd / 6;                        // 542
  const int NIMG = in_sizes[0] / 4096;         // 12288
  const int SP = NIMG / 3;                     // 4096
  const int Kp = (Kd + 63) & ~63;              // 3264

  char* ws = (char*)d_ws;
  unsigned short* post16 = (unsigned short*)ws;            // 4608 (region 9216)
  __hip_bfloat16* Tt = (__hip_bfloat16*)(ws + 9216);       // 80*64*2 = 10240
  __hip_bfloat16* Ub = (__hip_bfloat16*)(ws + 19456);      // 128*128*2 = 32768
  __hip_bfloat16* wB = (__hip_bfloat16*)(ws + 52224);      // ENC*Kp*2
  size_t wBytes = (size_t)ENC * Kp * 2;
  __hip_bfloat16* feats = (__hip_bfloat16*)(ws + 52224 + wBytes);

  setup_tables_kernel<<<1, 256, 0, stream>>>(post16, Tt, Ub);
  wconv_kernel<<<1024, 256, 0, stream>>>(W, wB, ENC, Kd, Kp);
  fft_mfma_kernel<<<NIMG / IMGS, 128, 0, stream>>>(x, Tt, Ub, post16, feats, K, Kp);
  gemm_bias_kernel<<<(SP / BM) * (ENC / BN), 256, 0, stream>>>(feats, wB, bias, out, SP, ENC, Kp);
}

// Round 7
// 199.990 us; speedup vs baseline: 1.7106x; 1.7106x over previous
//
#include <hip/hip_runtime.h>
#include <hip/hip_bf16.h>
#include <math.h>

typedef float f32x4 __attribute__((ext_vector_type(4)));
typedef __bf16 bf16x8 __attribute__((ext_vector_type(8)));
typedef unsigned short u16x8 __attribute__((ext_vector_type(8)));

#define PI2 6.283185307179586

static __device__ __forceinline__ unsigned short f2b(float f) {
  __hip_bfloat16 h = __float2bfloat16(f);
  return reinterpret_cast<unsigned short&>(h);
}

static __device__ __forceinline__ bf16x8 pack8(float4 a, float4 b) {
  u16x8 t;
  t[0] = f2b(a.x); t[1] = f2b(a.y); t[2] = f2b(a.z); t[3] = f2b(a.w);
  t[4] = f2b(b.x); t[5] = f2b(b.y); t[6] = f2b(b.z); t[7] = f2b(b.w);
  return __builtin_bit_cast(bf16x8, t);
}

// ---------------- setup: pos table (ushort [64][36]) + twiddle tables ----------------
__global__ __launch_bounds__(256) void setup_tables_kernel(
    unsigned short* __restrict__ post16, __hip_bfloat16* __restrict__ Tt,
    __hip_bfloat16* __restrict__ Ub) {
  const int tid = threadIdx.x;
  __shared__ int cnt[64];
  __shared__ int pref[64];

  if (tid < 64) {
    int i = tid;
    double ys = -1.0 + (double)i * (2.0 / 63.0);
    int cRow = 0;
    for (int j = 0; j < 33; ++j) {
      double xs = (double)j / 32.0;
      bool m = (fabs(xs) < 0.1) || (fabs(ys) < 0.1) || (xs * xs + ys * ys <= 0.16);
      cRow += m ? 1 : 0;
    }
    cnt[i] = cRow;
  }
  __syncthreads();
  if (tid == 0) {
    int s = 0;
    for (int i = 0; i < 64; ++i) { pref[i] = s; s += cnt[i]; }
  }
  __syncthreads();
  if (tid < 64) {
    int i = tid;
    int k = pref[i];
    double ys = -1.0 + (double)i * (2.0 / 63.0);
    for (int j = 0; j < 36; ++j) {
      unsigned short v = 0xFFFFu;
      if (j < 33) {
        double xs = (double)j / 32.0;
        bool m = (fabs(xs) < 0.1) || (fabs(ys) < 0.1) || (xs * xs + ys * ys <= 0.16);
        if (m) v = (unsigned short)(k++);
      }
      post16[i * 36 + j] = v;
    }
  }

  // Tt[80][64]: rows 0..32 = cos(2*pi*n*w/64), rows 40..72 = -sin, else 0
  for (int idx = tid; idx < 80 * 64; idx += 256) {
    int n = idx >> 6, w = idx & 63;
    float v = 0.0f;
    if (n < 33) {
      int r = (n * w) & 63;
      v = cosf((float)(PI2 / 64.0) * (float)r);
    } else if (n >= 40 && n < 73) {
      int r = ((n - 40) * w) & 63;
      v = -sinf((float)(PI2 / 64.0) * (float)r);
    }
    Tt[idx] = __float2bfloat16(v);
  }

  // Ub[128][128]: row u'=u   : [cos | sin], row u'=64+u : [-sin | cos], v=(u+32)&63
  for (int idx = tid; idx < 128 * 128; idx += 256) {
    int up = idx >> 7, kk = idx & 127;
    int u = up & 63;
    int vfreq = (u + 32) & 63;
    int h = kk & 63;
    int r = (vfreq * h) & 63;
    float cv, sv;
    __sincosf((float)(PI2 / 64.0) * (float)r, &sv, &cv);
    float val;
    if (up < 64) val = (kk < 64) ? cv : sv;
    else         val = (kk < 64) ? -sv : cv;
    Ub[idx] = __float2bfloat16(val);
  }
}

// ---------------- weight fp32 -> bf16, K-padded (B^T layout) ----------------
__global__ __launch_bounds__(256) void wconv_kernel(
    const float* __restrict__ W, __hip_bfloat16* __restrict__ wB,
    int N, int Kd, int Kp) {
  int total = N * Kp;
  for (int idx = blockIdx.x * 256 + threadIdx.x; idx < total; idx += gridDim.x * 256) {
    int e = idx / Kp;
    int f = idx - e * Kp;
    float v = (f < Kd) ? W[(size_t)e * Kd + f] : 0.0f;
    wB[idx] = __float2bfloat16(v);
  }
}

// -------- fused MFMA rfft2 + fftshift + gather: 2 waves/image, 16 images/block --------
// x prefetched HBM->LDS fp32 via global_load_lds double-buffer with counted
// vmcnt(8) (loads stay in flight across the whole iteration). Source addresses
// pre-swizzled (granule ^= row&7) so linear DMA yields a bank-spread layout;
// phase B reads fp32 straight from staging and converts in-register.
// LDS: stg 2*16384 + Sout 8704 + featbuf 2176 + post 4608 = 48256 -> 3 blocks/CU.
#define IMGS 16
#define STG 16384
#define POSTB 4608

__global__ __launch_bounds__(128, 2) void fft_mfma_kernel(
    const float* __restrict__ x,
    const __hip_bfloat16* __restrict__ Tt,     // [80][64]
    const __hip_bfloat16* __restrict__ Ub,     // [128][128]
    const unsigned short* __restrict__ post16, // [64][36]
    __hip_bfloat16* __restrict__ feats,
    int K, int Kp) {
  __shared__ __align__(16) char lds[2 * STG + 8704 + 2176 + POSTB];
  const int tid = threadIdx.x;
  const int lane = tid & 63;
  const int wp = tid >> 6;     // wave 0/1: X-row half & u' half
  const int l4 = lane & 15;
  const int q = lane >> 4;
  char* stg0 = lds;
  char* stg1 = lds + STG;
  char* sout = lds + 2 * STG;                          // 34 rows x 256 B
  unsigned int* fb = (unsigned int*)(lds + 2 * STG + 8704);
  unsigned short* fbs = (unsigned short*)fb;
  unsigned short* postl = (unsigned short*)(lds + 2 * STG + 8704 + 2176);

  const int img0 = blockIdx.x * IMGS;

  // async-stage own half of an image: 8x 1KB DMA, source granule pre-swizzled
  auto issue8 = [&](const float* xi, char* dstbuf) {
    #pragma unroll
    for (int rr = 0; rr < 8; ++rr) {
      int row = wp * 32 + rr * 4 + q;
      int ggs = l4 ^ (row & 7);
      const float* g = xi + row * 64 + ggs * 4;
      char* l = dstbuf + (wp * 32 + rr * 4) * 256;     // wave-uniform base
      __builtin_amdgcn_global_load_lds(
          (const __attribute__((address_space(1))) void*)g,
          (__attribute__((address_space(3))) void*)l, 16, 0, 0);
    }
  };

  // prologue: image 0 -> stg0 (async), post table -> LDS
  issue8(x + (size_t)img0 * 4096, stg0);
  {
    const unsigned int* src = reinterpret_cast<const unsigned int*>(post16);
    unsigned int* dst = reinterpret_cast<unsigned int*>(postl);
    #pragma unroll
    for (int i = 0; i < 9; ++i) dst[i * 128 + tid] = src[i * 128 + tid];
  }

  for (int it = 0; it < IMGS; ++it) {
    const int img = img0 + it;
    const int sp = img / 3;
    const int c = img - sp * 3;
    char* sc = (it & 1) ? stg1 : stg0;
    char* sn = (it & 1) ? stg0 : stg1;

    // issue next image's DMA, then wait only for the OLD 8 (counted vmcnt)
    if (it + 1 < IMGS) {
      issue8(x + (size_t)(img + 1) * 4096, sn);
      asm volatile("s_waitcnt vmcnt(8)" ::: "memory");
    } else {
      asm volatile("s_waitcnt vmcnt(0)" ::: "memory");
    }

    // ---- phase B: stage 1 MFMA  S[own 32 rows][80] = X * Tt^T  (20 MFMA)
    // A-fragments read fp32 from staging (swizzled granules) + cvt in-register
    f32x4 acc1[2][5] = {};
    #pragma unroll
    for (int ks = 0; ks < 2; ++ks) {
      bf16x8 a1[2], b1[5];
      #pragma unroll
      for (int am = 0; am < 2; ++am) {
        int h = wp * 32 + am * 16 + l4;
        int g0 = ks * 8 + q * 2;
        float4 v0 = *reinterpret_cast<const float4*>(sc + h * 256 + ((g0 ^ (h & 7)) * 16));
        float4 v1 = *reinterpret_cast<const float4*>(sc + h * 256 + (((g0 + 1) ^ (h & 7)) * 16));
        a1[am] = pack8(v0, v1);
      }
      #pragma unroll
      for (int n = 0; n < 5; ++n) {
        int row = n * 16 + l4;
        b1[n] = *reinterpret_cast<const bf16x8*>(
            (const char*)Tt + row * 128 + ks * 64 + q * 16);
      }
      #pragma unroll
      for (int am = 0; am < 2; ++am)
        #pragma unroll
        for (int n = 0; n < 5; ++n)
          acc1[am][n] = __builtin_amdgcn_mfma_f32_16x16x32_bf16(a1[am], b1[n], acc1[am][n], 0, 0, 0);
    }

    // ---- phase C: write Sout[j<33][kk] (Re kk=h, Im kk=64+h), packed ushort4
    #pragma unroll
    for (int n = 0; n < 5; ++n) {
      int col = n * 16 + l4;
      bool isRe = (col < 33);
      bool isIm = (col >= 40 && col < 73);
      if (!(isRe || isIm)) continue;
      int j = isRe ? col : (col - 40);
      #pragma unroll
      for (int am = 0; am < 2; ++am) {
        int h0 = wp * 32 + am * 16 + q * 4;           // kk&7 stays in one 8-group
        int kk0 = isRe ? h0 : (h0 + 64);
        int off = j * 256 + (((kk0 >> 3) ^ (j & 15)) * 16 + (kk0 & 7) * 2);
        ushort4 b;
        b.x = f2b(acc1[am][n][0]); b.y = f2b(acc1[am][n][1]);
        b.z = f2b(acc1[am][n][2]); b.w = f2b(acc1[am][n][3]);
        *reinterpret_cast<ushort4*>(sout + off) = b;
      }
    }

    __syncthreads();   // bar2: Sout complete (both kk halves); postl visible (it=0)

    // ---- phase D: stage 2 MFMA  C2[48 j-rows][own u' half] = Sout * Ub^T  (48 MFMA)
    f32x4 acc2[3][4] = {};
    #pragma unroll
    for (int ks = 0; ks < 4; ++ks) {
      bf16x8 a2[3], b2[4];
      #pragma unroll
      for (int m = 0; m < 3; ++m) {
        int j = m * 16 + l4;
        if (j > 33) j = 33;                           // clamp into 34-row buffer
        int kg = ks * 4 + q;
        a2[m] = *reinterpret_cast<const bf16x8*>(sout + j * 256 + ((kg ^ (j & 15)) * 16));
      }
      #pragma unroll
      for (int n = 0; n < 4; ++n) {
        int rowg = (wp * 4 + n) * 16 + l4;
        b2[n] = *reinterpret_cast<const bf16x8*>(
            (const char*)Ub + rowg * 256 + ks * 64 + q * 16);
      }
      #pragma unroll
      for (int m = 0; m < 3; ++m)
        #pragma unroll
        for (int n = 0; n < 4; ++n)
          acc2[m][n] = __builtin_amdgcn_mfma_f32_16x16x32_bf16(a2[m], b2[n], acc2[m][n], 0, 0, 0);
    }

    // ---- phase E: masked gather -> featbuf (wave 0: Re, wave 1: Im)
    {
      const int base = wp ? K : 0;
      #pragma unroll
      for (int n = 0; n < 4; ++n) {
        int u = n * 16 + l4;
        #pragma unroll
        for (int m = 0; m < 3; ++m) {
          int j0 = m * 16 + q * 4;
          if (j0 > 32) continue;
          ushort4 kv = *reinterpret_cast<const ushort4*>(postl + u * 36 + j0);
          #pragma unroll
          for (int r = 0; r < 4; ++r) {
            int j = j0 + r;
            unsigned short k = (&kv.x)[r];
            if (j < 33 && k != 0xFFFFu)
              fbs[base + k] = f2b(acc2[m][n][r]);
          }
        }
      }
    }

    __syncthreads();   // bar3: featbuf complete; D's Sout reads done

    // ---- copy featbuf -> feats (two contiguous dword runs) + zero K-pad
    {
      size_t obase = (size_t)sp * Kp;
      unsigned int* gRe = reinterpret_cast<unsigned int*>(feats + obase + (size_t)c * K);
      unsigned int* gIm = reinterpret_cast<unsigned int*>(feats + obase + (size_t)3 * K + (size_t)c * K);
      const int KD2 = K / 2;   // 271 dwords per run
      for (int i = tid; i < KD2; i += 128) {
        gRe[i] = fb[i];
        gIm[i] = fb[KD2 + i];
      }
      if (wp == 0 && c == 2) {
        unsigned int* gp = reinterpret_cast<unsigned int*>(feats + obase + (size_t)6 * K);
        int padDw = (Kp - 6 * K) / 2;
        if (lane < padDw) gp[lane] = 0u;
      }
    }
    // next iteration: B reads only own DMA'd half (vmcnt-guarded); C-writes to
    // Sout are safe because passing bar3 implies the other wave finished D.
  }
}

// ---------------- bf16 MFMA GEMM: out[M][N] = A[M][Kp] * B[N][Kp]^T + bias ----------------
#define BM 128
#define BN 128
#define BKK 64

__global__ __launch_bounds__(256) void gemm_bias_kernel(
    const __hip_bfloat16* __restrict__ A, const __hip_bfloat16* __restrict__ B,
    const float* __restrict__ bias, float* __restrict__ C,
    int M, int N, int Kp) {
  __shared__ __align__(16) unsigned short As[BM * BKK];
  __shared__ __align__(16) unsigned short Bs[BN * BKK];

  const int tid = threadIdx.x;
  const int lane = tid & 63;
  const int wid = tid >> 6;
  const int wm = wid & 1;
  const int wn = wid >> 1;
  const int nbm = M / BM;
  const int bm = blockIdx.x % nbm;
  const int bn = blockIdx.x / nbm;
  const int row0A = bm * BM;
  const int row0B = bn * BN;

  f32x4 acc[4][4] = {};

  for (int k0 = 0; k0 < Kp; k0 += BKK) {
    #pragma unroll
    for (int i = 0; i < 4; ++i) {
      int qc = i * 256 + tid;
      int r = qc >> 3;
      int cb = (qc & 7) * 16;
      const char* gA = (const char*)A + ((size_t)(row0A + r) * Kp + k0) * 2 + cb;
      const char* gB = (const char*)B + ((size_t)(row0B + r) * Kp + k0) * 2 + cb;
      char* lA = (char*)As + (size_t)(i * 256 + wid * 64) * 16;
      char* lB = (char*)Bs + (size_t)(i * 256 + wid * 64) * 16;
      __builtin_amdgcn_global_load_lds((const __attribute__((address_space(1))) void*)gA,
                                       (__attribute__((address_space(3))) void*)lA, 16, 0, 0);
      __builtin_amdgcn_global_load_lds((const __attribute__((address_space(1))) void*)gB,
                                       (__attribute__((address_space(3))) void*)lB, 16, 0, 0);
    }
    __syncthreads();

    #pragma unroll
    for (int kk = 0; kk < 2; ++kk) {
      bf16x8 afr[4], bfr[4];
      const int ke = kk * 32 + (lane >> 4) * 8;
      #pragma unroll
      for (int m = 0; m < 4; ++m) {
        int rowA = wm * 64 + m * 16 + (lane & 15);
        afr[m] = *reinterpret_cast<const bf16x8*>(&As[rowA * BKK + ke]);
      }
      #pragma unroll
      for (int n = 0; n < 4; ++n) {
        int rowB = wn * 64 + n * 16 + (lane & 15);
        bfr[n] = *reinterpret_cast<const bf16x8*>(&Bs[rowB * BKK + ke]);
      }
      #pragma unroll
      for (int m = 0; m < 4; ++m)
        #pragma unroll
        for (int n = 0; n < 4; ++n)
          acc[m][n] = __builtin_amdgcn_mfma_f32_16x16x32_bf16(afr[m], bfr[n], acc[m][n], 0, 0, 0);
    }
    __syncthreads();
  }

  #pragma unroll
  for (int n = 0; n < 4; ++n) {
    int gcol = row0B + wn * 64 + n * 16 + (lane & 15);
    float bv = bias[gcol];
    #pragma unroll
    for (int m = 0; m < 4; ++m) {
      int grow0 = row0A + wm * 64 + m * 16 + (lane >> 4) * 4;
      #pragma unroll
      for (int r = 0; r < 4; ++r) {
        C[(size_t)(grow0 + r) * N + gcol] = acc[m][n][r] + bv;
      }
    }
  }
}

extern "C" void kernel_launch(void* const* d_in, const int* in_sizes, int n_in,
                              void* d_out, int out_size, void* d_ws, size_t ws_size,
                              hipStream_t stream) {
  const float* x = (const float*)d_in[0];
  const float* W = (const float*)d_in[2];
  const float* bias = (const float*)d_in[3];
  float* out = (float*)d_out;

  const int ENC = in_sizes[3];                 // 1024
  const int Kd = in_sizes[2] / ENC;            // 6*K = 3252
  const int K = Kd / 6;                        // 542
  const int NIMG = in_sizes[0] / 4096;         // 12288
  const int SP = NIMG / 3;                     // 4096
  const int Kp = (Kd + 63) & ~63;              // 3264

  char* ws = (char*)d_ws;
  unsigned short* post16 = (unsigned short*)ws;            // 4608 (region 9216)
  __hip_bfloat16* Tt = (__hip_bfloat16*)(ws + 9216);       // 80*64*2 = 10240
  __hip_bfloat16* Ub = (__hip_bfloat16*)(ws + 19456);      // 128*128*2 = 32768
  __hip_bfloat16* wB = (__hip_bfloat16*)(ws + 52224);      // ENC*Kp*2
  size_t wBytes = (size_t)ENC * Kp * 2;
  __hip_bfloat16* feats = (__hip_bfloat16*)(ws + 52224 + wBytes);

  setup_tables_kernel<<<1, 256, 0, stream>>>(post16, Tt, Ub);
  wconv_kernel<<<1024, 256, 0, stream>>>(W, wB, ENC, Kd, Kp);
  fft_mfma_kernel<<<NIMG / IMGS, 128, 0, stream>>>(x, Tt, Ub, post16, feats, K, Kp);
  gemm_bias_kernel<<<(SP / BM) * (ENC / BN), 256, 0, stream>>>(feats, wB, bias, out, SP, ENC, Kp);
}